// Round 12
// baseline (179.528 us; speedup 1.0000x reference)
//
#include <hip/hip_runtime.h>

#define DEV __device__ __forceinline__
#define MFMA(a, b, c) __builtin_amdgcn_mfma_f32_16x16x32_bf16(a, b, c, 0, 0, 0)

typedef __bf16 bf16x8 __attribute__((ext_vector_type(8)));
typedef float f32x4 __attribute__((ext_vector_type(4)));
typedef unsigned short u16x8 __attribute__((ext_vector_type(8)));

// ---------- helpers ----------
DEV float blo(unsigned u) { return __builtin_bit_cast(float, u << 16); }
DEV float bhi(unsigned u) { return __builtin_bit_cast(float, u & 0xFFFF0000u); }
DEV unsigned short f2b(float f) {
  unsigned u = __builtin_bit_cast(unsigned, f);
  return (unsigned short)((u + 0x7FFFu + ((u >> 16) & 1u)) >> 16);
}
DEV float sigf(float x) { return 1.0f / (1.0f + expf(-x)); }

DEV void llds16(const void* g, void* l) {
  __builtin_amdgcn_global_load_lds(
      (__attribute__((address_space(1))) void*)(void*)g,
      (__attribute__((address_space(3))) void*)l, 16, 0, 0);
}

// ---------- fused fp32 -> bf16 conversion (all 6 tensors, 1 launch) ----------
__global__ __launch_bounds__(256) void cvt_all_kernel(
    const float* __restrict__ x, const float* __restrict__ qw,
    const float* __restrict__ kw, const float* __restrict__ vw,
    const float* __restrict__ cw1, const float* __restrict__ ow,
    unsigned short* __restrict__ XB, unsigned short* __restrict__ WCAT,
    unsigned short* __restrict__ OWB) {
  const int i = blockIdx.x * 256 + threadIdx.x;
  const float* s;
  unsigned short* d;
  if (i < 2097152)      { s = x   + (size_t)i * 4;                 d = XB + (size_t)i * 4; }
  else if (i < 2359296) { size_t j = i - 2097152; s = qw  + j * 4; d = WCAT + j * 4; }
  else if (i < 2621440) { size_t j = i - 2359296; s = kw  + j * 4; d = WCAT + 1048576 + j * 4; }
  else if (i < 2883584) { size_t j = i - 2621440; s = vw  + j * 4; d = WCAT + 2097152 + j * 4; }
  else if (i < 2949120) { size_t j = i - 2883584; s = cw1 + j * 4; d = WCAT + 3145728 + j * 4; }
  else if (i < 3211264) { size_t j = i - 2949120; s = ow  + j * 4; d = OWB + j * 4; }
  else return;
  float4 f = *(const float4*)s;
  ushort4 o;
  o.x = f2b(f.x); o.y = f2b(f.y); o.z = f2b(f.z); o.w = f2b(f.w);
  *(ushort4*)d = o;
}

// ---------- 128x128 GEMM, BK=32, single-buffer 2-barrier, 16KB LDS ----------
// m97/m103-class config (their best 128² = BK=32, 16KB staging). 64B rows =
// 4x16B slots; swizzle slot = hi ^ ((row>>1)&3) — enumerated conflict-free
// (every 8-lane b128 group covers all 8 bank-positions); inverse applied on
// the llds16 global source. Bijective XCD swizzle, bn-fast. Cols >= act_col0:
// v=tanh(v+bias) -> Cout2 (dense ld=256); else Cout (stride ldC).
template <int OUTF>  // 0 = bf16 out, 1 = fp32 out
__global__ __launch_bounds__(256, 2) void gemm_bk32_kernel(
    const unsigned short* __restrict__ A, const unsigned short* __restrict__ B,
    void* __restrict__ Cout, unsigned short* __restrict__ Cout2,
    int K, int ldC, int act_col0, const float* __restrict__ bias, int nbn) {
  __shared__ char As[8192];   // 128 rows x 32 k bf16
  __shared__ char Bs[8192];
  const int tid = threadIdx.x;
  const int lane = tid & 63;
  const int w = tid >> 6;
  const int wr = w >> 1, wc = w & 1;
  const int ln15 = lane & 15, hi = lane >> 4;

  const int nwg = gridDim.x, orig = blockIdx.x;
  const int qd = nwg >> 3, rm = nwg & 7;
  const int xcd = orig & 7, loc = orig >> 3;
  const int swz = (xcd < rm ? xcd * (qd + 1) : rm * (qd + 1) + (xcd - rm) * qd) + loc;
  const int bn = swz % nbn, bm = swz / nbn;
  const int m0 = bm * 128, n0 = bn * 128;

  auto stage = [&](const unsigned short* src, int row0, int k0, char* dst) {
#pragma unroll
    for (int j = 0; j < 2; ++j) {
      const int slot = j * 256 + tid;            // 0..511 16B-slots
      const int rr = slot >> 2;                  // row 0..127
      const int kc = (slot & 3) ^ ((rr >> 1) & 3);  // inverse swizzle on source
      llds16(src + (size_t)(row0 + rr) * K + k0 + kc * 8, dst + slot * 16);
    }
  };
  auto rd = [&](const char* unit, int row) -> bf16x8 {
    const int sc = hi ^ ((row >> 1) & 3);
    return *(const bf16x8*)(unit + row * 64 + sc * 16);
  };

  f32x4 acc[4][4] = {};
  const int nk = K >> 5;
  for (int kt = 0; kt < nk; ++kt) {
    stage(A, m0, kt * 32, As);
    stage(B, n0, kt * 32, Bs);
    __syncthreads();
    bf16x8 af[4], bf[4];
#pragma unroll
    for (int i = 0; i < 4; ++i) {
      af[i] = rd(As, wr * 64 + i * 16 + ln15);
      bf[i] = rd(Bs, wc * 64 + i * 16 + ln15);
    }
#pragma unroll
    for (int i = 0; i < 4; ++i)
#pragma unroll
      for (int j = 0; j < 4; ++j)
        acc[i][j] = MFMA(af[i], bf[j], acc[i][j]);
    __syncthreads();
  }
  // epilogue: C/D layout col=lane&15, row=(lane>>4)*4+reg
#pragma unroll
  for (int i = 0; i < 4; ++i) {
    const int rowb = m0 + wr * 64 + i * 16 + hi * 4;
#pragma unroll
    for (int j = 0; j < 4; ++j) {
      const int col = n0 + wc * 64 + j * 16 + ln15;
#pragma unroll
      for (int r = 0; r < 4; ++r) {
        float v = acc[i][j][r];
        if (col >= act_col0) {
          v = tanhf(v + bias[col - act_col0]);
          Cout2[(size_t)(rowb + r) * 256 + (col - act_col0)] = f2b(v);
        } else {
          const size_t off = (size_t)(rowb + r) * ldC + col;
          if (OUTF == 0) ((unsigned short*)Cout)[off] = f2b(v);
          else ((float*)Cout)[off] = v;
        }
      }
    }
  }
}

// ---------- sensor layer 2: lc = sigmoid(h1 @ w2.T + b2), dense H1 ----------
__global__ __launch_bounds__(256) void sensor2_kernel(
    const unsigned short* __restrict__ H1, const float* __restrict__ w2,
    const float* __restrict__ b2, float* __restrict__ LC) {
  const int tid = threadIdx.x;
  const int h = tid & 15, r = tid >> 4;
  const int m = blockIdx.x * 16 + r;
  const unsigned short* hrow = H1 + (size_t)m * 256;
  const float* wrow = w2 + h * 256;
  float acc = 0.0f;
  for (int d = 0; d < 256; d += 8) {
    uint4 hv = *(const uint4*)(hrow + d);
    float4 wa = *(const float4*)(wrow + d);
    float4 wb = *(const float4*)(wrow + d + 4);
    acc = fmaf(blo(hv.x), wa.x, acc); acc = fmaf(bhi(hv.x), wa.y, acc);
    acc = fmaf(blo(hv.y), wa.z, acc); acc = fmaf(bhi(hv.y), wa.w, acc);
    acc = fmaf(blo(hv.z), wb.x, acc); acc = fmaf(bhi(hv.z), wb.y, acc);
    acc = fmaf(blo(hv.w), wb.z, acc); acc = fmaf(bhi(hv.w), wb.w, acc);
  }
  LC[(size_t)m * 16 + h] = sigf(acc + b2[h]);
}

// ---------- scan pass A (MFMA): MTB image [f][slot^f&7] bf16; P = prod lam ----------
__global__ __launch_bounds__(256) void scan_passA_kernel(
    const unsigned short* __restrict__ QKV, const float* __restrict__ LC,
    const float* __restrict__ decay, unsigned short* __restrict__ MTB,
    float* __restrict__ P) {
  __shared__ char SH[34304];
  ushort* kL = (ushort*)SH;
  ushort* vL = (ushort*)(SH + 8192);
  char* khT  = SH + 16384;
  char* vT   = SH + 24576;
  float* sigL = (float*)(SH + 32768);
  float* lcL  = (float*)(SH + 33024);
  float* Lp   = (float*)(SH + 33280);

  const int tid = threadIdx.x;
  const int c = blockIdx.x, h = blockIdx.y, b = blockIdx.z;
  const int t0 = c * 64;
#pragma unroll
  for (int i = 0; i < 2; ++i) {
    int idx = i * 256 + tid;
    int row = idx >> 3, ch = idx & 7;
    size_t g = (size_t)(b * 2048 + t0 + row) * 3072 + h * 64 + ch * 8;
    int lb = (i * 256 + (tid >> 6) * 64) * 16;
    llds16(QKV + g + 1024, (char*)kL + lb);
    llds16(QKV + g + 2048, (char*)vL + lb);
  }
  if (tid < 64) sigL[tid] = sigf(decay[h * 64 + tid]);
  else if (tid < 128) lcL[tid - 64] = LC[(size_t)(b * 2048 + t0 + tid - 64) * 16 + h];
  __syncthreads();

  const int e = tid & 63, seg = tid >> 6;
  const float sig_e = sigL[e];
  float lp = 1.f;
#pragma unroll
  for (int i = 0; i < 16; ++i)
    lp *= fminf(sig_e * (1.f + 0.2f * lcL[seg * 16 + i]), 0.9995f);
  Lp[seg * 64 + e] = lp;
  __syncthreads();
  float T = 1.f;
#pragma unroll
  for (int sg = 0; sg < 4; ++sg) if (sg > seg) T *= Lp[sg * 64 + e];

  u16x8 ka = {}, kb = {};
  float r = T;
#pragma unroll
  for (int i = 15; i >= 0; --i) {
    int s = seg * 16 + i;
    float lam = fminf(sig_e * (1.f + 0.2f * lcL[s]), 0.9995f);
    float kv = blo((unsigned)kL[s * 64 + e]) * r;
    if (i >= 8) kb[i - 8] = f2b(kv); else ka[i] = f2b(kv);
    r *= lam;
  }
  *(u16x8*)(khT + e * 128 + (((2 * seg + 0) ^ (e & 7)) * 16)) = ka;
  *(u16x8*)(khT + e * 128 + (((2 * seg + 1) ^ (e & 7)) * 16)) = kb;
  if (seg == 0) P[((size_t)((b * 16 + h) * 32 + c)) * 64 + e] = r;

  u16x8 va = {}, vb = {};
#pragma unroll
  for (int i = 0; i < 16; ++i) {
    unsigned short vv = vL[(seg * 16 + i) * 64 + e];
    if (i >= 8) vb[i - 8] = vv; else va[i] = vv;
  }
  *(u16x8*)(vT + e * 128 + (((2 * seg + 0) ^ (e & 7)) * 16)) = va;
  *(u16x8*)(vT + e * 128 + (((2 * seg + 1) ^ (e & 7)) * 16)) = vb;
  __syncthreads();

  const int ln15 = tid & 15, hi = (tid & 63) >> 4, w = tid >> 6;
  auto rd = [&](const char* u, int row, int ks) -> bf16x8 {
    return *(const bf16x8*)(u + row * 128 + (((ks * 4 + hi) ^ (row & 7)) * 16));
  };
  bf16x8 av0 = rd(vT, w * 16 + ln15, 0), av1 = rd(vT, w * 16 + ln15, 1);
  unsigned short* Mp = MTB + ((size_t)((b * 16 + h) * 32 + c)) * 4096;
#pragma unroll
  for (int er = 0; er < 4; ++er) {
    f32x4 acc = {};
    acc = MFMA(av0, rd(khT, er * 16 + ln15, 0), acc);
    acc = MFMA(av1, rd(khT, er * 16 + ln15, 1), acc);
    const int e2 = er * 16 + ln15;
#pragma unroll
    for (int rr = 0; rr < 4; ++rr) {
      const int f = w * 16 + hi * 4 + rr;
      Mp[f * 64 + (((e2 >> 3) ^ (f & 7)) << 3) + (e2 & 7)] = f2b(acc[rr]);
    }
  }
}

// ---------- scan pass B: chunk-state composition on bf16 image, fp32 carry ----------
__global__ __launch_bounds__(256) void scan_passB_kernel(
    unsigned short* __restrict__ MTB, const float* __restrict__ P) {
  const int bh = blockIdx.y;
  const int task = blockIdx.x * 256 + threadIdx.x;
  const int f = task >> 6, slot = (task >> 3) & 7, pos = task & 7;
  const int e = ((slot ^ (f & 7)) << 3) | pos;
  const size_t base = (size_t)bh * 32;
  float S = 0.0f;
  for (int c = 0; c < 32; ++c) {
    unsigned short* Mp = MTB + (base + c) * 4096 + task;
    const float p = P[(base + c) * 64 + e];
    const float m = blo((unsigned)*Mp);
    *Mp = f2b(S);
    S = fmaf(p, S, m);
  }
}

// ---------- scan pass C (MFMA): Y = Qh SinT^T + tril(Qh Kh^T) V ----------
__global__ __launch_bounds__(256) void scan_passC_kernel(
    const unsigned short* __restrict__ QKV, const float* __restrict__ LC,
    const float* __restrict__ decay, const unsigned short* __restrict__ MTB,
    unsigned short* __restrict__ Y) {
  __shared__ char SH[50688];
  ushort* qL = (ushort*)SH;
  ushort* kL = (ushort*)(SH + 8192);
  ushort* vL = (ushort*)(SH + 16384);
  char* qT = SH + 24576;
  char* kT = SH + 32768;
  char* vT = SH + 40960;
  char* Ab   = SH;
  char* sinT = SH + 8192;
  float* sigL = (float*)(SH + 49152);
  float* lcL  = (float*)(SH + 49408);
  float* Lp   = (float*)(SH + 49664);

  const int tid = threadIdx.x;
  const int c = blockIdx.x, h = blockIdx.y, b = blockIdx.z;
  const int t0 = c * 64;
#pragma unroll
  for (int i = 0; i < 2; ++i) {
    int idx = i * 256 + tid;
    int row = idx >> 3, ch = idx & 7;
    size_t g = (size_t)(b * 2048 + t0 + row) * 3072 + h * 64 + ch * 8;
    int lb = (i * 256 + (tid >> 6) * 64) * 16;
    llds16(QKV + g,        (char*)qL + lb);
    llds16(QKV + g + 1024, (char*)kL + lb);
    llds16(QKV + g + 2048, (char*)vL + lb);
  }
  if (tid < 64) sigL[tid] = sigf(decay[h * 64 + tid]);
  else if (tid < 128) lcL[tid - 64] = LC[(size_t)(b * 2048 + t0 + tid - 64) * 16 + h];
  __syncthreads();

  const int e = tid & 63, seg = tid >> 6;
  const float sig_e = sigL[e];
  float lam[16];
#pragma unroll
  for (int i = 0; i < 16; ++i)
    lam[i] = fminf(sig_e * (1.f + 0.2f * lcL[seg * 16 + i]), 0.9995f);
  float lp = 1.f;
#pragma unroll
  for (int i = 0; i < 16; ++i) lp *= lam[i];
  Lp[seg * 64 + e] = lp;
  __syncthreads();
  float a = 1.f;
#pragma unroll
  for (int sg = 0; sg < 4; ++sg) if (sg < seg) a *= Lp[sg * 64 + e];

  float ap = a;
#pragma unroll
  for (int i = 0; i < 16; ++i) {
    int t = seg * 16 + i;
    ap *= lam[i];
    float qv = blo((unsigned)qL[t * 64 + e]) * ap;
    int off = ((e >> 3) ^ (t & 7)) * 16 + (e & 7) * 2;
    *(unsigned short*)(qT + t * 128 + off) = f2b(qv);
  }
  const float inv_end = 1.0f / ap;
  float R = 1.f;
#pragma unroll
  for (int i = 15; i >= 0; --i) {
    int t = seg * 16 + i;
    float kv = blo((unsigned)kL[t * 64 + e]) * (R * inv_end);
    R *= lam[i];
    int off = ((e >> 3) ^ (t & 7)) * 16 + (e & 7) * 2;
    *(unsigned short*)(kT + t * 128 + off) = f2b(kv);
  }
  u16x8 va = {}, vb = {};
#pragma unroll
  for (int i = 0; i < 16; ++i) {
    unsigned short vv = vL[(seg * 16 + i) * 64 + e];
    if (i >= 8) vb[i - 8] = vv; else va[i] = vv;
  }
  *(u16x8*)(vT + e * 128 + (((2 * seg + 0) ^ (e & 7)) * 16)) = va;
  *(u16x8*)(vT + e * 128 + (((2 * seg + 1) ^ (e & 7)) * 16)) = vb;
  __syncthreads();

  {
    const unsigned short* Ms = MTB + ((size_t)((b * 16 + h) * 32 + c)) * 4096;
#pragma unroll
    for (int i = 0; i < 2; ++i)
      llds16(Ms + (size_t)(i * 256 + tid) * 8, sinT + (i * 256 + (tid >> 6) * 64) * 16);
  }
  const int ln15 = tid & 15, hi = (tid & 63) >> 4, w = tid >> 6;
  auto rd = [&](const char* u, int row, int ks) -> bf16x8 {
    return *(const bf16x8*)(u + row * 128 + (((ks * 4 + hi) ^ (row & 7)) * 16));
  };
  bf16x8 Aq0 = rd(qT, w * 16 + ln15, 0), Aq1 = rd(qT, w * 16 + ln15, 1);
  f32x4 acc1[4];
#pragma unroll
  for (int sr = 0; sr < 4; ++sr) {
    acc1[sr] = (f32x4){0.f, 0.f, 0.f, 0.f};
    if (sr <= w) {
      acc1[sr] = MFMA(Aq0, rd(kT, sr * 16 + ln15, 0), acc1[sr]);
      acc1[sr] = MFMA(Aq1, rd(kT, sr * 16 + ln15, 1), acc1[sr]);
    }
  }
#pragma unroll
  for (int sr = 0; sr < 4; ++sr)
#pragma unroll
    for (int rr = 0; rr < 4; ++rr) {
      int t = w * 16 + hi * 4 + rr;
      int s = sr * 16 + ln15;
      float v = 0.f;
      if (sr <= w && s <= t) v = acc1[sr][rr];
      *(unsigned short*)(Ab + t * 128 + (((s >> 3) ^ (t & 7)) * 16) + (s & 7) * 2) = f2b(v);
    }
  bf16x8 Aa0 = rd(Ab, w * 16 + ln15, 0), Aa1 = rd(Ab, w * 16 + ln15, 1);
  __syncthreads();

  f32x4 accY[4];
#pragma unroll
  for (int fr = 0; fr < 4; ++fr) {
    accY[fr] = (f32x4){0.f, 0.f, 0.f, 0.f};
    accY[fr] = MFMA(Aq0, rd(sinT, fr * 16 + ln15, 0), accY[fr]);
    accY[fr] = MFMA(Aq1, rd(sinT, fr * 16 + ln15, 1), accY[fr]);
    accY[fr] = MFMA(Aa0, rd(vT, fr * 16 + ln15, 0), accY[fr]);
    accY[fr] = MFMA(Aa1, rd(vT, fr * 16 + ln15, 1), accY[fr]);
  }
#pragma unroll
  for (int fr = 0; fr < 4; ++fr)
#pragma unroll
    for (int rr = 0; rr < 4; ++rr)
      Y[(size_t)(b * 2048 + t0 + w * 16 + hi * 4 + rr) * 1024 + h * 64 + fr * 16 + ln15]
        = f2b(accY[fr][rr]);
}

// ---------- host launch ----------
extern "C" void kernel_launch(void* const* d_in, const int* in_sizes, int n_in,
                              void* d_out, int out_size, void* d_ws, size_t ws_size,
                              hipStream_t stream) {
  (void)in_sizes; (void)n_in; (void)out_size; (void)ws_size;
  const float* x     = (const float*)d_in[0];
  const float* q_w   = (const float*)d_in[1];
  const float* k_w   = (const float*)d_in[2];
  const float* v_w   = (const float*)d_in[3];
  const float* o_w   = (const float*)d_in[4];
  const float* cs_w1 = (const float*)d_in[5];
  const float* cs_b1 = (const float*)d_in[6];
  const float* cs_w2 = (const float*)d_in[7];
  const float* cs_b2 = (const float*)d_in[8];
  const float* decay = (const float*)d_in[9];
  float* out = (float*)d_out;

  char* ws = (char*)d_ws;
  unsigned short* XB   = (unsigned short*)(ws);                 // 16,777,216
  unsigned short* WCAT = (unsigned short*)(ws + 16777216);
  unsigned short* OWB  = (unsigned short*)(ws + 23592960);
  unsigned short* QKV  = (unsigned short*)(ws + 25690112);      // stride 3072
  unsigned short* H1   = (unsigned short*)(ws + 76021760);
  float*          LCb  = (float*)(ws + 80216064);
  unsigned short* MTB  = (unsigned short*)(ws + 80740352);
  float*          Pb   = (float*)(ws + 97517568);
  unsigned short* YB   = (unsigned short*)(ws + 98041856);

  cvt_all_kernel<<<12544, 256, 0, stream>>>(x, q_w, k_w, v_w, cs_w1, o_w,
                                            XB, WCAT, OWB);

  // fused q|k|v|h1 GEMM: [8192x1024]@[3328x1024]^T; qkv->QKV(ld 3072), h1->H1
  gemm_bk32_kernel<0><<<1664, 256, 0, stream>>>(XB, WCAT, QKV, H1,
                                                1024, 3072, 3072, cs_b1, 26);
  sensor2_kernel<<<512, 256, 0, stream>>>(H1, cs_w2, cs_b2, LCb);

  scan_passA_kernel<<<dim3(32, 16, 4), 256, 0, stream>>>(QKV, LCb, decay, MTB, Pb);
  scan_passB_kernel<<<dim3(16, 64), 256, 0, stream>>>(MTB, Pb);
  scan_passC_kernel<<<dim3(32, 16, 4), 256, 0, stream>>>(QKV, LCb, decay, MTB, YB);

  gemm_bk32_kernel<1><<<512, 256, 0, stream>>>(YB, OWB, out, nullptr,
                                               1024, 1024, 1 << 30, nullptr, 8);
}

// Round 13
// 167.231 us; speedup vs baseline: 1.0735x; 1.0735x over previous
//
#include <hip/hip_runtime.h>

#define DEV __device__ __forceinline__
#define MFMA(a, b, c) __builtin_amdgcn_mfma_f32_16x16x32_bf16(a, b, c, 0, 0, 0)

typedef __bf16 bf16x8 __attribute__((ext_vector_type(8)));
typedef float f32x4 __attribute__((ext_vector_type(4)));
typedef unsigned short u16x8 __attribute__((ext_vector_type(8)));

// ---------- helpers ----------
DEV float blo(unsigned u) { return __builtin_bit_cast(float, u << 16); }
DEV float bhi(unsigned u) { return __builtin_bit_cast(float, u & 0xFFFF0000u); }
DEV unsigned short f2b(float f) {
  unsigned u = __builtin_bit_cast(unsigned, f);
  return (unsigned short)((u + 0x7FFFu + ((u >> 16) & 1u)) >> 16);
}
DEV float sigf(float x) { return 1.0f / (1.0f + expf(-x)); }

DEV void llds16(const void* g, void* l) {
  __builtin_amdgcn_global_load_lds(
      (__attribute__((address_space(1))) void*)(void*)g,
      (__attribute__((address_space(3))) void*)l, 16, 0, 0);
}

// ---------- fused fp32 -> bf16 conversion (all 6 tensors, 1 launch) ----------
__global__ __launch_bounds__(256) void cvt_all_kernel(
    const float* __restrict__ x, const float* __restrict__ qw,
    const float* __restrict__ kw, const float* __restrict__ vw,
    const float* __restrict__ cw1, const float* __restrict__ ow,
    unsigned short* __restrict__ XB, unsigned short* __restrict__ WCAT,
    unsigned short* __restrict__ OWB) {
  const int i = blockIdx.x * 256 + threadIdx.x;
  const float* s;
  unsigned short* d;
  if (i < 2097152)      { s = x   + (size_t)i * 4;                 d = XB + (size_t)i * 4; }
  else if (i < 2359296) { size_t j = i - 2097152; s = qw  + j * 4; d = WCAT + j * 4; }
  else if (i < 2621440) { size_t j = i - 2359296; s = kw  + j * 4; d = WCAT + 1048576 + j * 4; }
  else if (i < 2883584) { size_t j = i - 2621440; s = vw  + j * 4; d = WCAT + 2097152 + j * 4; }
  else if (i < 2949120) { size_t j = i - 2883584; s = cw1 + j * 4; d = WCAT + 3145728 + j * 4; }
  else if (i < 3211264) { size_t j = i - 2949120; s = ow  + j * 4; d = OWB + j * 4; }
  else return;
  float4 f = *(const float4*)s;
  ushort4 o;
  o.x = f2b(f.x); o.y = f2b(f.y); o.z = f2b(f.z); o.w = f2b(f.w);
  *(ushort4*)d = o;
}

// ---------- 128x128 GEMM, BK=64, single-buffer 2-barrier (proven best, r11) ----------
// C[m][n] = sum_k A[m][k]*B[n][k], row-major bf16. LDS rows = 128B = 8x16B
// slots; slot ^= (row&7) on BOTH the llds16 source and the ds_read (verified
// conflict-free pair). Bijective XCD swizzle, bn-fast. Cols >= act_col0:
// v=tanh(v+bias) -> Cout2 (dense ld=256); else Cout (stride ldC).
template <int OUTF>  // 0 = bf16 out, 1 = fp32 out
__global__ __launch_bounds__(256, 2) void gemm_bk64_kernel(
    const unsigned short* __restrict__ A, const unsigned short* __restrict__ B,
    void* __restrict__ Cout, unsigned short* __restrict__ Cout2,
    int K, int ldC, int act_col0, const float* __restrict__ bias, int nbn) {
  __shared__ char As[16384];
  __shared__ char Bs[16384];
  const int tid = threadIdx.x;
  const int lane = tid & 63;
  const int w = tid >> 6;
  const int wr = w >> 1, wc = w & 1;
  const int ln15 = lane & 15, hi = lane >> 4;

  const int nwg = gridDim.x, orig = blockIdx.x;
  const int qd = nwg >> 3, rm = nwg & 7;
  const int xcd = orig & 7, loc = orig >> 3;
  const int swz = (xcd < rm ? xcd * (qd + 1) : rm * (qd + 1) + (xcd - rm) * qd) + loc;
  const int bn = swz % nbn, bm = swz / nbn;
  const int m0 = bm * 128, n0 = bn * 128;

  auto stage = [&](const unsigned short* src, int row0, int k0, char* dst) {
#pragma unroll
    for (int j = 0; j < 4; ++j) {
      const int slot = j * 256 + tid;
      const int rr = slot >> 3;
      const int kc = (slot & 7) ^ (rr & 7);
      llds16(src + (size_t)(row0 + rr) * K + k0 + kc * 8, dst + slot * 16);
    }
  };
  auto rd = [&](const char* unit, int row, int ks) -> bf16x8 {
    const int kc = (ks * 4 + hi) ^ (row & 7);
    return *(const bf16x8*)(unit + row * 128 + kc * 16);
  };

  f32x4 acc[4][4] = {};
  const int nk = K >> 6;
  for (int kt = 0; kt < nk; ++kt) {
    stage(A, m0, kt * 64, As);
    stage(B, n0, kt * 64, Bs);
    __syncthreads();
    bf16x8 af[2][4], bf[2][4];
#pragma unroll
    for (int ks = 0; ks < 2; ++ks)
#pragma unroll
      for (int i = 0; i < 4; ++i) {
        af[ks][i] = rd(As, wr * 64 + i * 16 + ln15, ks);
        bf[ks][i] = rd(Bs, wc * 64 + i * 16 + ln15, ks);
      }
#pragma unroll
    for (int i = 0; i < 4; ++i)
#pragma unroll
      for (int j = 0; j < 4; ++j) {
        acc[i][j] = MFMA(af[0][i], bf[0][j], acc[i][j]);
        acc[i][j] = MFMA(af[1][i], bf[1][j], acc[i][j]);
      }
    __syncthreads();
  }
#pragma unroll
  for (int i = 0; i < 4; ++i) {
    const int rowb = m0 + wr * 64 + i * 16 + hi * 4;
#pragma unroll
    for (int j = 0; j < 4; ++j) {
      const int col = n0 + wc * 64 + j * 16 + ln15;
#pragma unroll
      for (int r = 0; r < 4; ++r) {
        float v = acc[i][j][r];
        if (col >= act_col0) {
          v = tanhf(v + bias[col - act_col0]);
          Cout2[(size_t)(rowb + r) * 256 + (col - act_col0)] = f2b(v);
        } else {
          const size_t off = (size_t)(rowb + r) * ldC + col;
          if (OUTF == 0) ((unsigned short*)Cout)[off] = f2b(v);
          else ((float*)Cout)[off] = v;
        }
      }
    }
  }
}

// ---------- sensor layer 2: lc = sigmoid(h1 @ w2.T + b2), dense H1 ----------
__global__ __launch_bounds__(256) void sensor2_kernel(
    const unsigned short* __restrict__ H1, const float* __restrict__ w2,
    const float* __restrict__ b2, float* __restrict__ LC) {
  const int tid = threadIdx.x;
  const int h = tid & 15, r = tid >> 4;
  const int m = blockIdx.x * 16 + r;
  const unsigned short* hrow = H1 + (size_t)m * 256;
  const float* wrow = w2 + h * 256;
  float acc = 0.0f;
  for (int d = 0; d < 256; d += 8) {
    uint4 hv = *(const uint4*)(hrow + d);
    float4 wa = *(const float4*)(wrow + d);
    float4 wb = *(const float4*)(wrow + d + 4);
    acc = fmaf(blo(hv.x), wa.x, acc); acc = fmaf(bhi(hv.x), wa.y, acc);
    acc = fmaf(blo(hv.y), wa.z, acc); acc = fmaf(bhi(hv.y), wa.w, acc);
    acc = fmaf(blo(hv.z), wb.x, acc); acc = fmaf(bhi(hv.z), wb.y, acc);
    acc = fmaf(blo(hv.w), wb.z, acc); acc = fmaf(bhi(hv.w), wb.w, acc);
  }
  LC[(size_t)m * 16 + h] = sigf(acc + b2[h]);
}

// ---------- scan pass A (MFMA): MTB image [f][slot^f&7] bf16; P = prod lam ----------
__global__ __launch_bounds__(256) void scan_passA_kernel(
    const unsigned short* __restrict__ QKV, const float* __restrict__ LC,
    const float* __restrict__ decay, unsigned short* __restrict__ MTB,
    float* __restrict__ P) {
  __shared__ char SH[34304];
  ushort* kL = (ushort*)SH;
  ushort* vL = (ushort*)(SH + 8192);
  char* khT  = SH + 16384;
  char* vT   = SH + 24576;
  float* sigL = (float*)(SH + 32768);
  float* lcL  = (float*)(SH + 33024);
  float* Lp   = (float*)(SH + 33280);

  const int tid = threadIdx.x;
  const int c = blockIdx.x, h = blockIdx.y, b = blockIdx.z;
  const int t0 = c * 64;
#pragma unroll
  for (int i = 0; i < 2; ++i) {
    int idx = i * 256 + tid;
    int row = idx >> 3, ch = idx & 7;
    size_t g = (size_t)(b * 2048 + t0 + row) * 3072 + h * 64 + ch * 8;
    int lb = (i * 256 + (tid >> 6) * 64) * 16;
    llds16(QKV + g + 1024, (char*)kL + lb);
    llds16(QKV + g + 2048, (char*)vL + lb);
  }
  if (tid < 64) sigL[tid] = sigf(decay[h * 64 + tid]);
  else if (tid < 128) lcL[tid - 64] = LC[(size_t)(b * 2048 + t0 + tid - 64) * 16 + h];
  __syncthreads();

  const int e = tid & 63, seg = tid >> 6;
  const float sig_e = sigL[e];
  float lp = 1.f;
#pragma unroll
  for (int i = 0; i < 16; ++i)
    lp *= fminf(sig_e * (1.f + 0.2f * lcL[seg * 16 + i]), 0.9995f);
  Lp[seg * 64 + e] = lp;
  __syncthreads();
  float T = 1.f;
#pragma unroll
  for (int sg = 0; sg < 4; ++sg) if (sg > seg) T *= Lp[sg * 64 + e];

  u16x8 ka = {}, kb = {};
  float r = T;
#pragma unroll
  for (int i = 15; i >= 0; --i) {
    int s = seg * 16 + i;
    float lam = fminf(sig_e * (1.f + 0.2f * lcL[s]), 0.9995f);
    float kv = blo((unsigned)kL[s * 64 + e]) * r;
    if (i >= 8) kb[i - 8] = f2b(kv); else ka[i] = f2b(kv);
    r *= lam;
  }
  *(u16x8*)(khT + e * 128 + (((2 * seg + 0) ^ (e & 7)) * 16)) = ka;
  *(u16x8*)(khT + e * 128 + (((2 * seg + 1) ^ (e & 7)) * 16)) = kb;
  if (seg == 0) P[((size_t)((b * 16 + h) * 32 + c)) * 64 + e] = r;

  u16x8 va = {}, vb = {};
#pragma unroll
  for (int i = 0; i < 16; ++i) {
    unsigned short vv = vL[(seg * 16 + i) * 64 + e];
    if (i >= 8) vb[i - 8] = vv; else va[i] = vv;
  }
  *(u16x8*)(vT + e * 128 + (((2 * seg + 0) ^ (e & 7)) * 16)) = va;
  *(u16x8*)(vT + e * 128 + (((2 * seg + 1) ^ (e & 7)) * 16)) = vb;
  __syncthreads();

  const int ln15 = tid & 15, hi = (tid & 63) >> 4, w = tid >> 6;
  auto rd = [&](const char* u, int row, int ks) -> bf16x8 {
    return *(const bf16x8*)(u + row * 128 + (((ks * 4 + hi) ^ (row & 7)) * 16));
  };
  bf16x8 av0 = rd(vT, w * 16 + ln15, 0), av1 = rd(vT, w * 16 + ln15, 1);
  unsigned short* Mp = MTB + ((size_t)((b * 16 + h) * 32 + c)) * 4096;
#pragma unroll
  for (int er = 0; er < 4; ++er) {
    f32x4 acc = {};
    acc = MFMA(av0, rd(khT, er * 16 + ln15, 0), acc);
    acc = MFMA(av1, rd(khT, er * 16 + ln15, 1), acc);
    const int e2 = er * 16 + ln15;
#pragma unroll
    for (int rr = 0; rr < 4; ++rr) {
      const int f = w * 16 + hi * 4 + rr;
      Mp[f * 64 + (((e2 >> 3) ^ (f & 7)) << 3) + (e2 & 7)] = f2b(acc[rr]);
    }
  }
}

// ---------- scan pass B: chunk-state composition on bf16 image, fp32 carry ----------
__global__ __launch_bounds__(256) void scan_passB_kernel(
    unsigned short* __restrict__ MTB, const float* __restrict__ P) {
  const int bh = blockIdx.y;
  const int task = blockIdx.x * 256 + threadIdx.x;
  const int f = task >> 6, slot = (task >> 3) & 7, pos = task & 7;
  const int e = ((slot ^ (f & 7)) << 3) | pos;
  const size_t base = (size_t)bh * 32;
  float S = 0.0f;
  for (int c = 0; c < 32; ++c) {
    unsigned short* Mp = MTB + (base + c) * 4096 + task;
    const float p = P[(base + c) * 64 + e];
    const float m = blo((unsigned)*Mp);
    *Mp = f2b(S);
    S = fmaf(p, S, m);
  }
}

// ---------- scan pass C (MFMA): Y = Qh SinT^T + tril(Qh Kh^T) V ----------
__global__ __launch_bounds__(256) void scan_passC_kernel(
    const unsigned short* __restrict__ QKV, const float* __restrict__ LC,
    const float* __restrict__ decay, const unsigned short* __restrict__ MTB,
    unsigned short* __restrict__ Y) {
  __shared__ char SH[50688];
  ushort* qL = (ushort*)SH;
  ushort* kL = (ushort*)(SH + 8192);
  ushort* vL = (ushort*)(SH + 16384);
  char* qT = SH + 24576;
  char* kT = SH + 32768;
  char* vT = SH + 40960;
  char* Ab   = SH;
  char* sinT = SH + 8192;
  float* sigL = (float*)(SH + 49152);
  float* lcL  = (float*)(SH + 49408);
  float* Lp   = (float*)(SH + 49664);

  const int tid = threadIdx.x;
  const int c = blockIdx.x, h = blockIdx.y, b = blockIdx.z;
  const int t0 = c * 64;
#pragma unroll
  for (int i = 0; i < 2; ++i) {
    int idx = i * 256 + tid;
    int row = idx >> 3, ch = idx & 7;
    size_t g = (size_t)(b * 2048 + t0 + row) * 3072 + h * 64 + ch * 8;
    int lb = (i * 256 + (tid >> 6) * 64) * 16;
    llds16(QKV + g,        (char*)qL + lb);
    llds16(QKV + g + 1024, (char*)kL + lb);
    llds16(QKV + g + 2048, (char*)vL + lb);
  }
  if (tid < 64) sigL[tid] = sigf(decay[h * 64 + tid]);
  else if (tid < 128) lcL[tid - 64] = LC[(size_t)(b * 2048 + t0 + tid - 64) * 16 + h];
  __syncthreads();

  const int e = tid & 63, seg = tid >> 6;
  const float sig_e = sigL[e];
  float lam[16];
#pragma unroll
  for (int i = 0; i < 16; ++i)
    lam[i] = fminf(sig_e * (1.f + 0.2f * lcL[seg * 16 + i]), 0.9995f);
  float lp = 1.f;
#pragma unroll
  for (int i = 0; i < 16; ++i) lp *= lam[i];
  Lp[seg * 64 + e] = lp;
  __syncthreads();
  float a = 1.f;
#pragma unroll
  for (int sg = 0; sg < 4; ++sg) if (sg < seg) a *= Lp[sg * 64 + e];

  float ap = a;
#pragma unroll
  for (int i = 0; i < 16; ++i) {
    int t = seg * 16 + i;
    ap *= lam[i];
    float qv = blo((unsigned)qL[t * 64 + e]) * ap;
    int off = ((e >> 3) ^ (t & 7)) * 16 + (e & 7) * 2;
    *(unsigned short*)(qT + t * 128 + off) = f2b(qv);
  }
  const float inv_end = 1.0f / ap;
  float R = 1.f;
#pragma unroll
  for (int i = 15; i >= 0; --i) {
    int t = seg * 16 + i;
    float kv = blo((unsigned)kL[t * 64 + e]) * (R * inv_end);
    R *= lam[i];
    int off = ((e >> 3) ^ (t & 7)) * 16 + (e & 7) * 2;
    *(unsigned short*)(kT + t * 128 + off) = f2b(kv);
  }
  u16x8 va = {}, vb = {};
#pragma unroll
  for (int i = 0; i < 16; ++i) {
    unsigned short vv = vL[(seg * 16 + i) * 64 + e];
    if (i >= 8) vb[i - 8] = vv; else va[i] = vv;
  }
  *(u16x8*)(vT + e * 128 + (((2 * seg + 0) ^ (e & 7)) * 16)) = va;
  *(u16x8*)(vT + e * 128 + (((2 * seg + 1) ^ (e & 7)) * 16)) = vb;
  __syncthreads();

  {
    const unsigned short* Ms = MTB + ((size_t)((b * 16 + h) * 32 + c)) * 4096;
#pragma unroll
    for (int i = 0; i < 2; ++i)
      llds16(Ms + (size_t)(i * 256 + tid) * 8, sinT + (i * 256 + (tid >> 6) * 64) * 16);
  }
  const int ln15 = tid & 15, hi = (tid & 63) >> 4, w = tid >> 6;
  auto rd = [&](const char* u, int row, int ks) -> bf16x8 {
    return *(const bf16x8*)(u + row * 128 + (((ks * 4 + hi) ^ (row & 7)) * 16));
  };
  bf16x8 Aq0 = rd(qT, w * 16 + ln15, 0), Aq1 = rd(qT, w * 16 + ln15, 1);
  f32x4 acc1[4];
#pragma unroll
  for (int sr = 0; sr < 4; ++sr) {
    acc1[sr] = (f32x4){0.f, 0.f, 0.f, 0.f};
    if (sr <= w) {
      acc1[sr] = MFMA(Aq0, rd(kT, sr * 16 + ln15, 0), acc1[sr]);
      acc1[sr] = MFMA(Aq1, rd(kT, sr * 16 + ln15, 1), acc1[sr]);
    }
  }
#pragma unroll
  for (int sr = 0; sr < 4; ++sr)
#pragma unroll
    for (int rr = 0; rr < 4; ++rr) {
      int t = w * 16 + hi * 4 + rr;
      int s = sr * 16 + ln15;
      float v = 0.f;
      if (sr <= w && s <= t) v = acc1[sr][rr];
      *(unsigned short*)(Ab + t * 128 + (((s >> 3) ^ (t & 7)) * 16) + (s & 7) * 2) = f2b(v);
    }
  bf16x8 Aa0 = rd(Ab, w * 16 + ln15, 0), Aa1 = rd(Ab, w * 16 + ln15, 1);
  __syncthreads();

  f32x4 accY[4];
#pragma unroll
  for (int fr = 0; fr < 4; ++fr) {
    accY[fr] = (f32x4){0.f, 0.f, 0.f, 0.f};
    accY[fr] = MFMA(Aq0, rd(sinT, fr * 16 + ln15, 0), accY[fr]);
    accY[fr] = MFMA(Aq1, rd(sinT, fr * 16 + ln15, 1), accY[fr]);
    accY[fr] = MFMA(Aa0, rd(vT, fr * 16 + ln15, 0), accY[fr]);
    accY[fr] = MFMA(Aa1, rd(vT, fr * 16 + ln15, 1), accY[fr]);
  }
#pragma unroll
  for (int fr = 0; fr < 4; ++fr)
#pragma unroll
    for (int rr = 0; rr < 4; ++rr)
      Y[(size_t)(b * 2048 + t0 + w * 16 + hi * 4 + rr) * 1024 + h * 64 + fr * 16 + ln15]
        = f2b(accY[fr][rr]);
}

// ---------- host launch ----------
extern "C" void kernel_launch(void* const* d_in, const int* in_sizes, int n_in,
                              void* d_out, int out_size, void* d_ws, size_t ws_size,
                              hipStream_t stream) {
  (void)in_sizes; (void)n_in; (void)out_size; (void)ws_size;
  const float* x     = (const float*)d_in[0];
  const float* q_w   = (const float*)d_in[1];
  const float* k_w   = (const float*)d_in[2];
  const float* v_w   = (const float*)d_in[3];
  const float* o_w   = (const float*)d_in[4];
  const float* cs_w1 = (const float*)d_in[5];
  const float* cs_b1 = (const float*)d_in[6];
  const float* cs_w2 = (const float*)d_in[7];
  const float* cs_b2 = (const float*)d_in[8];
  const float* decay = (const float*)d_in[9];
  float* out = (float*)d_out;

  char* ws = (char*)d_ws;
  unsigned short* XB   = (unsigned short*)(ws);                 // 16,777,216
  unsigned short* WCAT = (unsigned short*)(ws + 16777216);
  unsigned short* OWB  = (unsigned short*)(ws + 23592960);
  unsigned short* QKV  = (unsigned short*)(ws + 25690112);      // stride 3072
  unsigned short* H1   = (unsigned short*)(ws + 76021760);
  float*          LCb  = (float*)(ws + 80216064);
  unsigned short* MTB  = (unsigned short*)(ws + 80740352);
  float*          Pb   = (float*)(ws + 97517568);
  unsigned short* YB   = (unsigned short*)(ws + 98041856);

  cvt_all_kernel<<<12544, 256, 0, stream>>>(x, q_w, k_w, v_w, cs_w1, o_w,
                                            XB, WCAT, OWB);

  // fused q|k|v|h1 GEMM: [8192x1024]@[3328x1024]^T; qkv->QKV(ld 3072), h1->H1
  gemm_bk64_kernel<0><<<1664, 256, 0, stream>>>(XB, WCAT, QKV, H1,
                                                1024, 3072, 3072, cs_b1, 26);
  sensor2_kernel<<<512, 256, 0, stream>>>(H1, cs_w2, cs_b2, LCb);

  scan_passA_kernel<<<dim3(32, 16, 4), 256, 0, stream>>>(QKV, LCb, decay, MTB, Pb);
  scan_passB_kernel<<<dim3(16, 64), 256, 0, stream>>>(MTB, Pb);
  scan_passC_kernel<<<dim3(32, 16, 4), 256, 0, stream>>>(QKV, LCb, decay, MTB, YB);

  gemm_bk64_kernel<1><<<512, 256, 0, stream>>>(YB, OWB, out, nullptr,
                                               1024, 1024, 1 << 30, nullptr, 8);
}